// Round 9
// baseline (443.287 us; speedup 1.0000x reference)
//
#include <hip/hip_runtime.h>
#include <math.h>
#include <stdint.h>

// Problem dims (fixed by reference)
constexpr int Lz  = 4;
constexpr int Bb  = 128;
constexpr int STd = 512;
constexpr int Dd  = 1536;   // IN + CTX + ST
constexpr int Rr  = 256;
constexpr int Cc  = 256;

typedef __bf16 bf16x8 __attribute__((ext_vector_type(8)));
typedef float  f32x4  __attribute__((ext_vector_type(4)));

__device__ __forceinline__ float sigmoidf_(float v) { return 1.0f / (1.0f + expf(-v)); }

__device__ __forceinline__ uint32_t pkbf16(float a, float b) {
    uint32_t ua = __float_as_uint(a) + 0x8000u;
    uint32_t ub = __float_as_uint(b) + 0x8000u;
    return __builtin_amdgcn_perm(ub, ua, 0x07060302u);
}
__device__ __forceinline__ uint4 cvt8(const float4 lo, const float4 hi) {
    uint4 r;
    r.x = pkbf16(lo.x, lo.y); r.y = pkbf16(lo.z, lo.w);
    r.z = pkbf16(hi.x, hi.y); r.w = pkbf16(hi.z, hi.w);
    return r;
}

// ============================================================================
// Fused kernel: 1024 blocks.
//   blocks   0..255 : gate (h_new), then join mupd queue
//   blocks 256..511 : u/v projections (spin on gate flags), then join queue
//   blocks 512..1023: mupd chunks from dynamic queue (spin per-btile on uv flags)
// Flags in d_ws (zeroed by captured hipMemsetAsync). Device-scope
// release/acquire atomics for cross-XCD visibility (G16). Co-residency of all
// 1024 blocks is capacity-guaranteed (4 blocks/CU), so one-way producer->
// consumer spinning cannot deadlock.
// ============================================================================
__global__ __launch_bounds__(256, 4) void k_all(
    const float* __restrict__ x, const float* __restrict__ c, const float* __restrict__ h,
    const f32x4* __restrict__ M,
    const float* __restrict__ phi_w, const float* __restrict__ phi_b,
    const float* __restrict__ alpha_w, const float* __restrict__ alpha_b,
    const float* __restrict__ beta_w, const float* __restrict__ beta_b,
    const float* __restrict__ u_w, const float* __restrict__ u_b,
    const float* __restrict__ v_w, const float* __restrict__ v_b,
    const float* __restrict__ gl, const float* __restrict__ el,
    float* __restrict__ h_new, f32x4* __restrict__ Mout,
    unsigned* __restrict__ flags, float* __restrict__ u_out, float* __restrict__ v_out)
{
    __shared__ __align__(16) char smem[16384 + 512 + 16];

    const int bid = blockIdx.x;
    const int tid = threadIdx.x;

    // ---------------- role: gate ----------------
    if (bid < 256) {
        uint32_t* lds = (uint32_t*)smem;   // A:[0,1024) B0/B1/B2:+1024 each
        const int l  = bid >> 6;
        const int by = (bid >> 4) & 3;
        const int b0 = by * 32;
        const int o0 = (bid & 15) * 32;

        const int rowblk = tid >> 7;
        const int kstep  = (tid >> 6) & 1;
        const int ls     = tid & 63;
        const int mrow   = (rowblk << 4) | (ls & 15);
        const int kd     = kstep * 32 + ((ls >> 4) << 3);
        const int slot_u = tid * 4;

        const float* wrow0 = phi_w   + (size_t)(l * STd + o0 + mrow) * Dd + kd;
        const float* wrow1 = alpha_w + (size_t)(l * STd + o0 + mrow) * Dd + kd;
        const float* wrow2 = beta_w  + (size_t)(l * STd + o0 + mrow) * Dd + kd;
        const float* abase0 = x + (size_t)(b0 + mrow) * 512 + kd;
        const float* abase1 = c + (size_t)(b0 + mrow) * 512 + kd - 512;
        const float* abase2 = h + (size_t)(l * Bb + b0 + mrow) * 512 + kd - 1024;

        float4 paA0, paA1, pbA00, pbA01, pbA10, pbA11, pbA20, pbA21;
        float4 paB0, paB1, pbB00, pbB01, pbB10, pbB11, pbB20, pbB21;

        auto issueA = [&](int kk) {
            const float* p = (kk < 512 ? abase0 : (kk < 1024 ? abase1 : abase2)) + kk;
            paA0 = *(const float4*)p;  paA1 = *(const float4*)(p + 4);
            pbA00 = *(const float4*)(wrow0 + kk); pbA01 = *(const float4*)(wrow0 + kk + 4);
            pbA10 = *(const float4*)(wrow1 + kk); pbA11 = *(const float4*)(wrow1 + kk + 4);
            pbA20 = *(const float4*)(wrow2 + kk); pbA21 = *(const float4*)(wrow2 + kk + 4);
        };
        auto issueB = [&](int kk) {
            const float* p = (kk < 512 ? abase0 : (kk < 1024 ? abase1 : abase2)) + kk;
            paB0 = *(const float4*)p;  paB1 = *(const float4*)(p + 4);
            pbB00 = *(const float4*)(wrow0 + kk); pbB01 = *(const float4*)(wrow0 + kk + 4);
            pbB10 = *(const float4*)(wrow1 + kk); pbB11 = *(const float4*)(wrow1 + kk + 4);
            pbB20 = *(const float4*)(wrow2 + kk); pbB21 = *(const float4*)(wrow2 + kk + 4);
        };

        const int lane = tid & 63;
        const int w    = tid >> 6;
        const int m    = w >> 1;
        const int n    = w & 1;

        f32x4 acc[3] = {};

        auto mfma_step = [&]() {
            #pragma unroll
            for (int ks = 0; ks < 2; ++ks) {
                bf16x8 af  = *(bf16x8*)&lds[((m * 2 + ks) * 64 + lane) * 4];
                bf16x8 bf0 = *(bf16x8*)&lds[1024 + ((n * 2 + ks) * 64 + lane) * 4];
                bf16x8 bf1 = *(bf16x8*)&lds[2048 + ((n * 2 + ks) * 64 + lane) * 4];
                bf16x8 bf2 = *(bf16x8*)&lds[3072 + ((n * 2 + ks) * 64 + lane) * 4];
                acc[0] = __builtin_amdgcn_mfma_f32_16x16x32_bf16(af, bf0, acc[0], 0, 0, 0);
                acc[1] = __builtin_amdgcn_mfma_f32_16x16x32_bf16(af, bf1, acc[1], 0, 0, 0);
                acc[2] = __builtin_amdgcn_mfma_f32_16x16x32_bf16(af, bf2, acc[2], 0, 0, 0);
            }
        };

        issueA(0);
        issueB(64);
        for (int kk = 0; kk < Dd; kk += 128) {
            *(uint4*)&lds[slot_u]        = cvt8(paA0, paA1);
            *(uint4*)&lds[1024 + slot_u] = cvt8(pbA00, pbA01);
            *(uint4*)&lds[2048 + slot_u] = cvt8(pbA10, pbA11);
            *(uint4*)&lds[3072 + slot_u] = cvt8(pbA20, pbA21);
            __syncthreads();
            if (kk + 128 < Dd) issueA(kk + 128);
            mfma_step();
            __syncthreads();
            *(uint4*)&lds[slot_u]        = cvt8(paB0, paB1);
            *(uint4*)&lds[1024 + slot_u] = cvt8(pbB00, pbB01);
            *(uint4*)&lds[2048 + slot_u] = cvt8(pbB10, pbB11);
            *(uint4*)&lds[3072 + slot_u] = cvt8(pbB20, pbB21);
            __syncthreads();
            if (kk + 192 < Dd) issueB(kk + 192);
            mfma_step();
            __syncthreads();
        }

        const int bout = b0 + m * 16 + (lane >> 4) * 4;
        const int ocol = o0 + n * 16 + (lane & 15);
        const float pbias = phi_b[l * STd + ocol];
        const float abias = alpha_b[l * STd + ocol];
        const float bbias = beta_b[l * STd + ocol];
        #pragma unroll
        for (int r = 0; r < 4; ++r) {
            const int b = bout + r;
            float phi = acc[0][r] + pbias;
            float al  = sigmoidf_(acc[1][r] + abias);
            float be  = sigmoidf_(acc[2][r] + bbias);
            float ho  = h[(size_t)(l * Bb + b) * STd + ocol];
            h_new[(size_t)(l * Bb + b) * STd + ocol] = al * tanhf(phi) + be * ho;
        }

        __threadfence();
        __syncthreads();
        if (tid == 0)
            __hip_atomic_fetch_add(&flags[(l << 2) | by], 1u,
                                   __ATOMIC_RELEASE, __HIP_MEMORY_SCOPE_AGENT);
    }
    // ---------------- role: u/v ----------------
    else if (bid < 512) {
        uint32_t* lds = (uint32_t*)smem;   // A:[0,1024) B:[1024,2048)
        const int i   = bid - 256;
        const int l   = i >> 6;
        const int by  = (i >> 4) & 3;
        const int b0  = by * 32;
        const int n0g = (i & 15) * 32;

        if (tid == 0) {
            while (__hip_atomic_load(&flags[(l << 2) | by],
                                     __ATOMIC_ACQUIRE, __HIP_MEMORY_SCOPE_AGENT) < 16u)
                __builtin_amdgcn_s_sleep(8);
        }
        __syncthreads();

        const float* W; const float* bias; float* out; int o_base;
        if (n0g < Rr) { W = u_w; bias = u_b; out = u_out; o_base = n0g; }
        else          { W = v_w; bias = v_b; out = v_out; o_base = n0g - Rr; }

        const int rowblk = tid >> 7;
        const int kstep  = (tid >> 6) & 1;
        const int ls     = tid & 63;
        const int mrow   = (rowblk << 4) | (ls & 15);
        const int kd     = kstep * 32 + ((ls >> 4) << 3);
        const int slot_u = tid * 4;

        const float* wrow   = W + (size_t)(l * Rr + o_base + mrow) * Dd + kd;
        const float* abase0 = h_new + (size_t)(l * Bb + b0 + mrow) * 512 + kd;
        const float* abase1 = x + (size_t)(b0 + mrow) * 512 + kd - 512;
        const float* abase2 = c + (size_t)(b0 + mrow) * 512 + kd - 1024;

        float4 paA0, paA1, pbA0, pbA1;
        float4 paB0, paB1, pbB0, pbB1;
        auto issueA = [&](int kk) {
            const float* p = (kk < 512 ? abase0 : (kk < 1024 ? abase1 : abase2)) + kk;
            paA0 = *(const float4*)p;  paA1 = *(const float4*)(p + 4);
            pbA0 = *(const float4*)(wrow + kk); pbA1 = *(const float4*)(wrow + kk + 4);
        };
        auto issueB = [&](int kk) {
            const float* p = (kk < 512 ? abase0 : (kk < 1024 ? abase1 : abase2)) + kk;
            paB0 = *(const float4*)p;  paB1 = *(const float4*)(p + 4);
            pbB0 = *(const float4*)(wrow + kk); pbB1 = *(const float4*)(wrow + kk + 4);
        };

        const int lane = tid & 63;
        const int w    = tid >> 6;
        const int m    = w >> 1;
        const int n    = w & 1;

        f32x4 acc = {};
        auto mfma_step = [&]() {
            #pragma unroll
            for (int ks = 0; ks < 2; ++ks) {
                bf16x8 af = *(bf16x8*)&lds[((m * 2 + ks) * 64 + lane) * 4];
                bf16x8 bf = *(bf16x8*)&lds[1024 + ((n * 2 + ks) * 64 + lane) * 4];
                acc = __builtin_amdgcn_mfma_f32_16x16x32_bf16(af, bf, acc, 0, 0, 0);
            }
        };

        issueA(0);
        issueB(64);
        for (int kk = 0; kk < Dd; kk += 128) {
            *(uint4*)&lds[slot_u]        = cvt8(paA0, paA1);
            *(uint4*)&lds[1024 + slot_u] = cvt8(pbA0, pbA1);
            __syncthreads();
            if (kk + 128 < Dd) issueA(kk + 128);
            mfma_step();
            __syncthreads();
            *(uint4*)&lds[slot_u]        = cvt8(paB0, paB1);
            *(uint4*)&lds[1024 + slot_u] = cvt8(pbB0, pbB1);
            __syncthreads();
            if (kk + 192 < Dd) issueB(kk + 192);
            mfma_step();
            __syncthreads();
        }

        const int bout = b0 + m * 16 + (lane >> 4) * 4;
        const int ocol = o_base + n * 16 + (lane & 15);
        const float bv = bias[l * Rr + ocol];
        #pragma unroll
        for (int r = 0; r < 4; ++r)
            out[(size_t)(l * Bb + bout + r) * Rr + ocol] = acc[r] + bv;

        __threadfence();
        __syncthreads();
        if (tid == 0)
            __hip_atomic_fetch_add(&flags[16 + by], 1u,
                                   __ATOMIC_RELEASE, __HIP_MEMORY_SCOPE_AGENT);
    }

    // ---------------- all blocks: mupd chunk queue ----------------
    {
        constexpr int SL = Bb * Rr * Cc / 4;   // float4 per level
        constexpr int CH = 2048;               // float4 sites per chunk per level
        constexpr int NI = CH / 256;           // 8 iterations

        f32x4 (*buf)[256] = (f32x4(*)[256])smem;          // 16 KB
        float* su         = (float*)(smem + 16384);       // [4][32]
        unsigned* s_chunk = (unsigned*)(smem + 16384 + 512);

        const int w    = tid >> 6;             // wave index == level
        const int lane = tid & 63;

        const int lu = (w == 0) ? 0 : w - 1;
        const int ld = (w == 3) ? 3 : w + 1;
        const float g  = sigmoidf_(gl[w]);
        const float e  = sigmoidf_(el[w]);
        const float og = 1.0f - g;
        const float gh = g * 0.5f;

        for (;;) {
            __syncthreads();                   // protect smem reuse
            if (tid == 0)
                *s_chunk = __hip_atomic_fetch_add(&flags[20], 1u,
                                                  __ATOMIC_RELAXED, __HIP_MEMORY_SCOPE_AGENT);
            __syncthreads();
            const unsigned cidx = *s_chunk;
            if (cidx >= 1024u) break;

            const int b     = cidx >> 3;
            const int rbase = (cidx & 7) * 32;

            if (tid == 0) {
                while (__hip_atomic_load(&flags[16 + (b >> 5)],
                                         __ATOMIC_ACQUIRE, __HIP_MEMORY_SCOPE_AGENT) < 64u)
                    __builtin_amdgcn_s_sleep(8);
            }
            __syncthreads();

            if (tid < 128) {
                int l = tid >> 5, rl = tid & 31;
                su[l * 32 + rl] = u_out[(l * Bb + b) * Rr + rbase + rl];
            }
            const f32x4 vv = *(const f32x4*)&v_out[((w * Bb + b) * (Cc / 4) + lane) * 4];

            const f32x4* Mw = M    + (size_t)w * SL + (size_t)cidx * CH + lane;
            f32x4*       Mo = Mout + (size_t)w * SL + (size_t)cidx * CH + lane;

            f32x4 p0, p1, p2, p3;
            auto issue = [&](int j) {
                const f32x4* q = Mw + j * 256;
                p0 = __builtin_nontemporal_load(q);
                p1 = __builtin_nontemporal_load(q + 64);
                p2 = __builtin_nontemporal_load(q + 128);
                p3 = __builtin_nontemporal_load(q + 192);
            };

            issue(0);
            __syncthreads();                   // su ready
            #pragma unroll 1
            for (int j = 0; j < NI; ++j) {
                const f32x4 c0 = p0, c1 = p1, c2 = p2, c3 = p3;
                buf[w][0 * 64 + lane] = p0;
                buf[w][1 * 64 + lane] = p1;
                buf[w][2 * 64 + lane] = p2;
                buf[w][3 * 64 + lane] = p3;
                __syncthreads();
                if (j + 1 < NI) issue(j + 1);

                const f32x4 cc[4] = { c0, c1, c2, c3 };
                #pragma unroll
                for (int tt = 0; tt < 4; ++tt) {
                    const f32x4 mc  = cc[tt];
                    const f32x4 mu_ = buf[lu][tt * 64 + lane];
                    const f32x4 md  = buf[ld][tt * 64 + lane];
                    const float euu = e * su[w * 32 + j * 4 + tt];
                    f32x4 o;
                    o[0] = og * mc[0] + gh * (mu_[0] + md[0]) + euu * vv[0];
                    o[1] = og * mc[1] + gh * (mu_[1] + md[1]) + euu * vv[1];
                    o[2] = og * mc[2] + gh * (mu_[2] + md[2]) + euu * vv[2];
                    o[3] = og * mc[3] + gh * (mu_[3] + md[3]) + euu * vv[3];
                    Mo[j * 256 + tt * 64] = o;
                }
                __syncthreads();
            }
        }
    }
}

extern "C" void kernel_launch(void* const* d_in, const int* in_sizes, int n_in,
                              void* d_out, int out_size, void* d_ws, size_t ws_size,
                              hipStream_t stream) {
    const float* x       = (const float*)d_in[0];
    const float* c       = (const float*)d_in[1];
    const float* h       = (const float*)d_in[2];
    const float* M       = (const float*)d_in[3];
    const float* phi_w   = (const float*)d_in[4];
    const float* phi_b   = (const float*)d_in[5];
    const float* alpha_w = (const float*)d_in[6];
    const float* alpha_b = (const float*)d_in[7];
    const float* beta_w  = (const float*)d_in[8];
    const float* beta_b  = (const float*)d_in[9];
    const float* u_w     = (const float*)d_in[10];
    const float* u_b     = (const float*)d_in[11];
    const float* v_w     = (const float*)d_in[12];
    const float* v_b     = (const float*)d_in[13];
    const float* gl      = (const float*)d_in[14];
    const float* el      = (const float*)d_in[15];

    float* out   = (float*)d_out;
    float* h_new = out;                          // L*B*ST
    float* M_new = out + Lz * Bb * STd;          // L*B*R*C

    unsigned* flags = (unsigned*)d_ws;           // 4 KB flag region
    float* u = (float*)((char*)d_ws + 4096);     // L*B*R
    float* v = u + Lz * Bb * Rr;                 // L*B*C

    hipMemsetAsync(d_ws, 0, 4096, stream);       // zero flags (graph-capturable)
    k_all<<<1024, 256, 0, stream>>>(
        x, c, h, (const f32x4*)M,
        phi_w, phi_b, alpha_w, alpha_b, beta_w, beta_b,
        u_w, u_b, v_w, v_b, gl, el,
        h_new, (f32x4*)M_new, flags, u, v);
}

// Round 10
// 89.616 us; speedup vs baseline: 4.9465x; 4.9465x over previous
//
#include <hip/hip_runtime.h>
#include <math.h>
#include <stdint.h>

// Problem dims (fixed by reference)
constexpr int Lz  = 4;
constexpr int Bb  = 128;
constexpr int STd = 512;
constexpr int Dd  = 1536;   // IN + CTX + ST
constexpr int Rr  = 256;
constexpr int Cc  = 256;

typedef __bf16 bf16x8 __attribute__((ext_vector_type(8)));
typedef float  f32x4  __attribute__((ext_vector_type(4)));

__device__ __forceinline__ float sigmoidf_(float v) { return 1.0f / (1.0f + expf(-v)); }

// pack two f32 -> dword of 2 bf16 (round-half-up via +0x8000, then v_perm high halves)
__device__ __forceinline__ uint32_t pkbf16(float a, float b) {
    uint32_t ua = __float_as_uint(a) + 0x8000u;
    uint32_t ub = __float_as_uint(b) + 0x8000u;
    return __builtin_amdgcn_perm(ub, ua, 0x07060302u);  // lo16=bf16(a), hi16=bf16(b)
}
__device__ __forceinline__ uint4 cvt8(const float4 lo, const float4 hi) {
    uint4 r;
    r.x = pkbf16(lo.x, lo.y); r.y = pkbf16(lo.z, lo.w);
    r.z = pkbf16(hi.x, hi.y); r.w = pkbf16(hi.z, hi.w);
    return r;
}

// ============================================================================
// Phase 1: gated state update via bf16 MFMA, depth-2 register prefetch.
// ============================================================================
__global__ __launch_bounds__(256) void k_gate(
    const float* __restrict__ x, const float* __restrict__ c, const float* __restrict__ h,
    const float* __restrict__ phi_w, const float* __restrict__ phi_b,
    const float* __restrict__ alpha_w, const float* __restrict__ alpha_b,
    const float* __restrict__ beta_w, const float* __restrict__ beta_b,
    float* __restrict__ h_new)
{
    __shared__ uint32_t lds[4096];  // A: [0,1024) uints ; B arr a: [1024*(1+a), +1024)

    const int l  = blockIdx.z;
    const int b0 = blockIdx.y * 32;
    const int o0 = blockIdx.x * 32;
    const int t  = threadIdx.x;

    const int rowblk = t >> 7;
    const int kstep  = (t >> 6) & 1;
    const int ls     = t & 63;
    const int mrow   = (rowblk << 4) | (ls & 15);
    const int kd     = kstep * 32 + ((ls >> 4) << 3);
    const int slot_u = t * 4;

    const float* wrow0 = phi_w   + (size_t)(l * STd + o0 + mrow) * Dd + kd;
    const float* wrow1 = alpha_w + (size_t)(l * STd + o0 + mrow) * Dd + kd;
    const float* wrow2 = beta_w  + (size_t)(l * STd + o0 + mrow) * Dd + kd;

    const float* abase0 = x + (size_t)(b0 + mrow) * 512 + kd;
    const float* abase1 = c + (size_t)(b0 + mrow) * 512 + kd - 512;
    const float* abase2 = h + (size_t)(l * Bb + b0 + mrow) * 512 + kd - 1024;

    float4 paA0, paA1, pbA00, pbA01, pbA10, pbA11, pbA20, pbA21;
    float4 paB0, paB1, pbB00, pbB01, pbB10, pbB11, pbB20, pbB21;

    auto issueA = [&](int kk) {
        const float* p = (kk < 512 ? abase0 : (kk < 1024 ? abase1 : abase2)) + kk;
        paA0 = *(const float4*)p;  paA1 = *(const float4*)(p + 4);
        pbA00 = *(const float4*)(wrow0 + kk); pbA01 = *(const float4*)(wrow0 + kk + 4);
        pbA10 = *(const float4*)(wrow1 + kk); pbA11 = *(const float4*)(wrow1 + kk + 4);
        pbA20 = *(const float4*)(wrow2 + kk); pbA21 = *(const float4*)(wrow2 + kk + 4);
    };
    auto issueB = [&](int kk) {
        const float* p = (kk < 512 ? abase0 : (kk < 1024 ? abase1 : abase2)) + kk;
        paB0 = *(const float4*)p;  paB1 = *(const float4*)(p + 4);
        pbB00 = *(const float4*)(wrow0 + kk); pbB01 = *(const float4*)(wrow0 + kk + 4);
        pbB10 = *(const float4*)(wrow1 + kk); pbB11 = *(const float4*)(wrow1 + kk + 4);
        pbB20 = *(const float4*)(wrow2 + kk); pbB21 = *(const float4*)(wrow2 + kk + 4);
    };

    const int lane = t & 63;
    const int w    = t >> 6;
    const int m    = w >> 1;      // A 16-row block
    const int n    = w & 1;       // B 16-col block

    f32x4 acc[3] = {};

    auto mfma_step = [&]() {
        #pragma unroll
        for (int ks = 0; ks < 2; ++ks) {
            bf16x8 af  = *(bf16x8*)&lds[((m * 2 + ks) * 64 + lane) * 4];
            bf16x8 bf0 = *(bf16x8*)&lds[1024 + ((n * 2 + ks) * 64 + lane) * 4];
            bf16x8 bf1 = *(bf16x8*)&lds[2048 + ((n * 2 + ks) * 64 + lane) * 4];
            bf16x8 bf2 = *(bf16x8*)&lds[3072 + ((n * 2 + ks) * 64 + lane) * 4];
            acc[0] = __builtin_amdgcn_mfma_f32_16x16x32_bf16(af, bf0, acc[0], 0, 0, 0);
            acc[1] = __builtin_amdgcn_mfma_f32_16x16x32_bf16(af, bf1, acc[1], 0, 0, 0);
            acc[2] = __builtin_amdgcn_mfma_f32_16x16x32_bf16(af, bf2, acc[2], 0, 0, 0);
        }
    };

    issueA(0);
    issueB(64);
    for (int kk = 0; kk < Dd; kk += 128) {
        *(uint4*)&lds[slot_u]        = cvt8(paA0, paA1);
        *(uint4*)&lds[1024 + slot_u] = cvt8(pbA00, pbA01);
        *(uint4*)&lds[2048 + slot_u] = cvt8(pbA10, pbA11);
        *(uint4*)&lds[3072 + slot_u] = cvt8(pbA20, pbA21);
        __syncthreads();
        if (kk + 128 < Dd) issueA(kk + 128);
        mfma_step();
        __syncthreads();
        *(uint4*)&lds[slot_u]        = cvt8(paB0, paB1);
        *(uint4*)&lds[1024 + slot_u] = cvt8(pbB00, pbB01);
        *(uint4*)&lds[2048 + slot_u] = cvt8(pbB10, pbB11);
        *(uint4*)&lds[3072 + slot_u] = cvt8(pbB20, pbB21);
        __syncthreads();
        if (kk + 192 < Dd) issueB(kk + 192);
        mfma_step();
        __syncthreads();
    }

    const int bout = b0 + m * 16 + (lane >> 4) * 4;
    const int ocol = o0 + n * 16 + (lane & 15);
    const float pbias = phi_b[l * STd + ocol];
    const float abias = alpha_b[l * STd + ocol];
    const float bbias = beta_b[l * STd + ocol];
    #pragma unroll
    for (int r = 0; r < 4; ++r) {
        const int b = bout + r;
        float phi = acc[0][r] + pbias;
        float al  = sigmoidf_(acc[1][r] + abias);
        float be  = sigmoidf_(acc[2][r] + bbias);
        float ho  = h[(size_t)(l * Bb + b) * STd + ocol];
        h_new[(size_t)(l * Bb + b) * STd + ocol] = al * tanhf(phi) + be * ho;
    }
}

// ============================================================================
// Phase 2: u,v projections via bf16 MFMA, depth-2 register prefetch.
// ============================================================================
__global__ __launch_bounds__(256) void k_uv(
    const float* __restrict__ x, const float* __restrict__ c,
    const float* __restrict__ h_new,
    const float* __restrict__ u_w, const float* __restrict__ u_b,
    const float* __restrict__ v_w, const float* __restrict__ v_b,
    float* __restrict__ u_out, float* __restrict__ v_out)
{
    __shared__ uint32_t lds[2048];  // A: [0,1024) ; B: [1024,2048)

    const int l   = blockIdx.z;
    const int b0  = blockIdx.y * 32;
    const int n0g = blockIdx.x * 32;   // 0..511 over [u | v]
    const int t   = threadIdx.x;

    const float* W; const float* bias; float* out; int o_base;
    if (n0g < Rr) { W = u_w; bias = u_b; out = u_out; o_base = n0g; }
    else          { W = v_w; bias = v_b; out = v_out; o_base = n0g - Rr; }

    const int rowblk = t >> 7;
    const int kstep  = (t >> 6) & 1;
    const int ls     = t & 63;
    const int mrow   = (rowblk << 4) | (ls & 15);
    const int kd     = kstep * 32 + ((ls >> 4) << 3);
    const int slot_u = t * 4;

    const float* wrow = W + (size_t)(l * Rr + o_base + mrow) * Dd + kd;
    const float* abase0 = h_new + (size_t)(l * Bb + b0 + mrow) * 512 + kd;
    const float* abase1 = x + (size_t)(b0 + mrow) * 512 + kd - 512;
    const float* abase2 = c + (size_t)(b0 + mrow) * 512 + kd - 1024;

    float4 paA0, paA1, pbA0, pbA1;
    float4 paB0, paB1, pbB0, pbB1;

    auto issueA = [&](int kk) {
        const float* p = (kk < 512 ? abase0 : (kk < 1024 ? abase1 : abase2)) + kk;
        paA0 = *(const float4*)p;  paA1 = *(const float4*)(p + 4);
        pbA0 = *(const float4*)(wrow + kk); pbA1 = *(const float4*)(wrow + kk + 4);
    };
    auto issueB = [&](int kk) {
        const float* p = (kk < 512 ? abase0 : (kk < 1024 ? abase1 : abase2)) + kk;
        paB0 = *(const float4*)p;  paB1 = *(const float4*)(p + 4);
        pbB0 = *(const float4*)(wrow + kk); pbB1 = *(const float4*)(wrow + kk + 4);
    };

    const int lane = t & 63;
    const int w    = t >> 6;
    const int m    = w >> 1;
    const int n    = w & 1;

    f32x4 acc = {};

    auto mfma_step = [&]() {
        #pragma unroll
        for (int ks = 0; ks < 2; ++ks) {
            bf16x8 af = *(bf16x8*)&lds[((m * 2 + ks) * 64 + lane) * 4];
            bf16x8 bf = *(bf16x8*)&lds[1024 + ((n * 2 + ks) * 64 + lane) * 4];
            acc = __builtin_amdgcn_mfma_f32_16x16x32_bf16(af, bf, acc, 0, 0, 0);
        }
    };

    issueA(0);
    issueB(64);
    for (int kk = 0; kk < Dd; kk += 128) {
        *(uint4*)&lds[slot_u]        = cvt8(paA0, paA1);
        *(uint4*)&lds[1024 + slot_u] = cvt8(pbA0, pbA1);
        __syncthreads();
        if (kk + 128 < Dd) issueA(kk + 128);
        mfma_step();
        __syncthreads();
        *(uint4*)&lds[slot_u]        = cvt8(paB0, paB1);
        *(uint4*)&lds[1024 + slot_u] = cvt8(pbB0, pbB1);
        __syncthreads();
        if (kk + 192 < Dd) issueB(kk + 192);
        mfma_step();
        __syncthreads();
    }

    const int bout = b0 + m * 16 + (lane >> 4) * 4;
    const int ocol = o_base + n * 16 + (lane & 15);
    const float bv = bias[l * Rr + ocol];
    #pragma unroll
    for (int r = 0; r < 4; ++r) {
        out[(size_t)(l * Bb + bout + r) * Rr + ocol] = acc[r] + bv;
    }
}

// ============================================================================
// Phase 3: EMA memory write — wave-per-level, copy-like streams (best variant).
// Block = 4 waves; wave w owns level w. Per iteration each wave loads a 4 KB
// contiguous run of its level into regs -> LDS, barrier, computes its level
// from LDS (neighbor coupling via LDS, not extra DRAM streams), NT-stores a
// 4 KB contiguous run. Each M line read exactly once, written exactly once.
// ============================================================================
__global__ __launch_bounds__(256) void k_mupd(
    const float4* __restrict__ M, const float* __restrict__ u, const float4* __restrict__ v,
    const float* __restrict__ gl, const float* __restrict__ el,
    float4* __restrict__ Mout)
{
    constexpr int SL = Bb * Rr * Cc / 4;   // float4 per level
    constexpr int CH = 2048;               // float4 sites per block per level
    constexpr int NI = CH / 256;           // 8 iterations

    __shared__ float4 buf[4][256];         // one iteration's sites, all 4 levels
    __shared__ float  su[4][32];           // u for this block's 32 r rows

    const int bid  = blockIdx.x;
    const int tid  = threadIdx.x;
    const int w    = tid >> 6;             // wave index == level
    const int lane = tid & 63;

    const int b     = bid >> 3;            // 8 blocks per batch index
    const int rbase = (bid & 7) * 32;

    if (tid < 128) {
        int l = tid >> 5, rl = tid & 31;
        su[l][rl] = u[(l * Bb + b) * Rr + rbase + rl];
    }

    // v depends only on (level, b, c4) and c4 == lane here: one reg per thread
    const float4 vv = v[(w * Bb + b) * (Cc / 4) + lane];

    const int lu = (w == 0) ? 0 : w - 1;
    const int ld = (w == 3) ? 3 : w + 1;
    const float g  = sigmoidf_(gl[w]);
    const float e  = sigmoidf_(el[w]);
    const float og = 1.0f - g;
    const float gh = g * 0.5f;

    const float4* Mw = M    + (size_t)w * SL + (size_t)bid * CH + lane;
    float4*       Mo = Mout + (size_t)w * SL + (size_t)bid * CH + lane;

    float4 p0, p1, p2, p3;
    auto issue = [&](int j) {
        const float4* q = Mw + j * 256;
        p0 = q[0]; p1 = q[64]; p2 = q[128]; p3 = q[192];
    };

    issue(0);
    #pragma unroll 1
    for (int j = 0; j < NI; ++j) {
        // own-level values kept in regs; LDS serves the neighbor levels
        const float4 c0 = p0, c1 = p1, c2 = p2, c3 = p3;
        buf[w][0 * 64 + lane] = p0;
        buf[w][1 * 64 + lane] = p1;
        buf[w][2 * 64 + lane] = p2;
        buf[w][3 * 64 + lane] = p3;
        __syncthreads();
        if (j + 1 < NI) issue(j + 1);      // next 4 KB in flight under compute

        const float4 cc[4] = { c0, c1, c2, c3 };
        #pragma unroll
        for (int t = 0; t < 4; ++t) {
            const float4 mc  = cc[t];
            const float4 mu_ = buf[lu][t * 64 + lane];
            const float4 md  = buf[ld][t * 64 + lane];
            const float  euu = e * su[w][j * 4 + t];
            f32x4 o;
            o[0] = og * mc.x + gh * (mu_.x + md.x) + euu * vv.x;
            o[1] = og * mc.y + gh * (mu_.y + md.y) + euu * vv.y;
            o[2] = og * mc.z + gh * (mu_.z + md.z) + euu * vv.z;
            o[3] = og * mc.w + gh * (mu_.w + md.w) + euu * vv.w;
            __builtin_nontemporal_store(o, (f32x4*)(Mo + j * 256 + t * 64));
        }
        __syncthreads();
    }
}

extern "C" void kernel_launch(void* const* d_in, const int* in_sizes, int n_in,
                              void* d_out, int out_size, void* d_ws, size_t ws_size,
                              hipStream_t stream) {
    const float* x       = (const float*)d_in[0];
    const float* c       = (const float*)d_in[1];
    const float* h       = (const float*)d_in[2];
    const float* M       = (const float*)d_in[3];
    const float* phi_w   = (const float*)d_in[4];
    const float* phi_b   = (const float*)d_in[5];
    const float* alpha_w = (const float*)d_in[6];
    const float* alpha_b = (const float*)d_in[7];
    const float* beta_w  = (const float*)d_in[8];
    const float* beta_b  = (const float*)d_in[9];
    const float* u_w     = (const float*)d_in[10];
    const float* u_b     = (const float*)d_in[11];
    const float* v_w     = (const float*)d_in[12];
    const float* v_b     = (const float*)d_in[13];
    const float* gl      = (const float*)d_in[14];
    const float* el      = (const float*)d_in[15];

    float* out   = (float*)d_out;
    float* h_new = out;                          // L*B*ST
    float* M_new = out + Lz * Bb * STd;          // L*B*R*C

    float* u = (float*)d_ws;                     // L*B*R
    float* v = u + Lz * Bb * Rr;                 // L*B*C

    k_gate<<<dim3(STd / 32, Bb / 32, Lz), 256, 0, stream>>>(
        x, c, h, phi_w, phi_b, alpha_w, alpha_b, beta_w, beta_b, h_new);
    k_uv<<<dim3((Rr + Cc) / 32, Bb / 32, Lz), 256, 0, stream>>>(
        x, c, h_new, u_w, u_b, v_w, v_b, u, v);
    // 1024 blocks; block owns 2048 sites (32 KB/level); wave w handles level w
    k_mupd<<<1024, 256, 0, stream>>>(
        (const float4*)M, u, (const float4*)v, gl, el, (float4*)M_new);
}